// Round 12
// baseline (103.156 us; speedup 1.0000x reference)
//
#include <hip/hip_runtime.h>

#define N_NODES 100000
#define N_EDGES 1600000
#define D_FEAT  64
#define NFEAT_ELEM (N_NODES * D_FEAT)                    // 6,400,000

#define BUCK_SHIFT 6
#define BUCK_NODES 64
#define NBUCK ((N_NODES + BUCK_NODES - 1) / BUCK_NODES)  // 1563
#define NB1 (NBUCK + 1)

#define CHUNK   4096
#define NCHUNK  ((N_EDGES + CHUNK - 1) / CHUNK)          // 391
#define BIN_BLK 256
#define BIN_EPT (CHUNK / BIN_BLK)                        // 16
#define SCAN_PER ((NBUCK + BIN_BLK - 1) / BIN_BLK)       // 7
#define PREP_BLOCKS 128

#define GB_BLK  256
#define GB_CAP  1536                                     // mean bucket 1024, +16 sigma

// transpose tiling
#define TT_CT ((NCHUNK + 63) / 64)                       // 7
#define TT_BT ((NB1 + 63) / 64)                          // 25

typedef float          vf4 __attribute__((ext_vector_type(4)));
typedef float          vf2 __attribute__((ext_vector_type(2)));
typedef int            vi2 __attribute__((ext_vector_type(2)));
typedef unsigned short vu4 __attribute__((ext_vector_type(4)));
typedef unsigned short ushort_t;

// ---------------------------------------------------------------------------
// Workspace: tbl (chunk-major run offsets) | tblT (bucket-major transpose) |
//            ep (chunk-major sorted payload) | featb (bf16 feat).
// ---------------------------------------------------------------------------
#define TBL_BYTES  (NCHUNK * NB1 * 2)
#define OFF_TBL    0
#define OFF_TBLT   (((OFF_TBL + TBL_BYTES) + 255) & ~255)
#define OFF_EP     (((OFF_TBLT + NB1 * NCHUNK * 2) + 255) & ~255)
#define OFF_FEATB  (OFF_EP + N_EDGES * 8)
#define WS_MED     (size_t)OFF_FEATB
#define WS_FULL    (size_t)(OFF_FEATB + (size_t)NFEAT_ELEM * 2)

// Chunk-major binning + fused bf16 prep (role-split grid).
template <int BF16>
__global__ __launch_bounds__(BIN_BLK) void k_bin(const int* __restrict__ src,
                                                 const int* __restrict__ dst,
                                                 const float* __restrict__ weight,
                                                 const float* __restrict__ feat,
                                                 ushort_t* __restrict__ featb,
                                                 ushort_t* __restrict__ tbl,
                                                 vi2* __restrict__ ep) {
    if (blockIdx.x >= NCHUNK) {                          // prep role
        if (!BF16) return;
        const int stride = PREP_BLOCKS * BIN_BLK;
        for (int i = (blockIdx.x - NCHUNK) * BIN_BLK + threadIdx.x;
             i < NFEAT_ELEM / 4; i += stride) {
            vf4 x = ((const vf4*)feat)[i];
            vu4 r;
#pragma unroll
            for (int k = 0; k < 4; ++k) {
                unsigned bb = __float_as_uint(x[k]);
                r[k] = (ushort_t)((bb + 0x7fffu + ((bb >> 16) & 1u)) >> 16);
            }
            __builtin_nontemporal_store(r, (vu4*)featb + i);
        }
        return;
    }

    __shared__ vi2 schunk[CHUNK];                        // 32 KB
    __shared__ int lcnt[NBUCK];                          // 6.25 KB
    __shared__ int ss[BIN_BLK];
    const int t = threadIdx.x;
    const int c = blockIdx.x;
    const int e0 = c * CHUNK;
    const int chunkN = (N_EDGES - e0 < CHUNK) ? (N_EDGES - e0) : CHUNK;

    for (int i = t; i < NBUCK; i += BIN_BLK) lcnt[i] = 0;
    __syncthreads();

    int bk[BIN_EPT], rk[BIN_EPT], xk[BIN_EPT], wk[BIN_EPT];
#pragma unroll
    for (int k = 0; k < BIN_EPT; ++k) {
        const int e = e0 + t + k * BIN_BLK;              // coalesced
        bk[k] = -1;
        if (e < N_EDGES) {
            int v = __builtin_nontemporal_load(dst + e);
            int s = __builtin_nontemporal_load(src + e);
            wk[k] = __builtin_nontemporal_load((const int*)weight + e);
            bk[k] = v >> BUCK_SHIFT;
            xk[k] = ((v & (BUCK_NODES - 1)) << 24) | s;  // src < 2^17
            rk[k] = atomicAdd(&lcnt[bk[k]], 1);
        }
    }
    __syncthreads();

    // blocked exclusive scan of lcnt (1563) -> in-place starts + table row
    int v7[SCAN_PER];
    const int lo = t * SCAN_PER;
    int s = 0;
#pragma unroll
    for (int k = 0; k < SCAN_PER; ++k) {
        const int i = lo + k;
        v7[k] = (i < NBUCK) ? lcnt[i] : 0;
        s += v7[k];
    }
    ss[t] = s;
    __syncthreads();
    for (int off = 1; off < BIN_BLK; off <<= 1) {
        int x = (t >= off) ? ss[t - off] : 0;
        __syncthreads();
        ss[t] += x;
        __syncthreads();
    }
    int run = ss[t] - s;
    ushort_t* row = tbl + (size_t)c * NB1;
#pragma unroll
    for (int k = 0; k < SCAN_PER; ++k) {
        const int i = lo + k;
        if (i < NBUCK) {
            row[i] = (ushort_t)run;
            lcnt[i] = run;
            run += v7[k];
        }
    }
    if (t == BIN_BLK - 1) row[NBUCK] = (ushort_t)chunkN;
    __syncthreads();

#pragma unroll
    for (int k = 0; k < BIN_EPT; ++k)
        if (bk[k] >= 0) schunk[lcnt[bk[k]] + rk[k]] = (vi2){xk[k], wk[k]};
    __syncthreads();

    for (int i = t; i < chunkN; i += BIN_BLK)            // contiguous stream
        __builtin_nontemporal_store(schunk[i], ep + e0 + i);
}

// 64x64 LDS-tiled transpose: tbl[c][b] (chunk-major) -> tblT[b][c]
// (bucket-major), so each gather block reads its offsets contiguously.
__global__ __launch_bounds__(256) void k_ttrans(const ushort_t* __restrict__ tbl,
                                                ushort_t* __restrict__ tblT) {
    __shared__ ushort_t tile[64][65];
    const int t = threadIdx.x;
    const int c0 = (blockIdx.x % TT_CT) * 64;
    const int b0 = (blockIdx.x / TT_CT) * 64;
    for (int idx = t; idx < 4096; idx += 256) {
        int cl = idx >> 6, bl = idx & 63;                // consecutive bl -> coalesced
        int c = c0 + cl, bb = b0 + bl;
        tile[bl][cl] = (c < NCHUNK && bb < NB1) ? tbl[(size_t)c * NB1 + bb] : (ushort_t)0;
    }
    __syncthreads();
    for (int idx = t; idx < 4096; idx += 256) {
        int bl = idx >> 6, cl = idx & 63;                // consecutive cl -> coalesced
        int c = c0 + cl, bb = b0 + bl;
        if (c < NCHUNK && bb < NB1) tblT[(size_t)bb * NCHUNK + c] = tile[bl][cl];
    }
}

// One block per 64-node bucket. Phase 1: walk 391 table runs (2 chunks per
// thread, offsets from contiguous tblT rows), deterministic staging via
// run-length scan. Phase 2-4: LDS count/scan/scatter into node-sorted list.
// Phase 5: register accumulation with half-wave pair trick; one NT float2
// store per node, bias fused. No global atomics on the hot path.
template <int BF16>
__global__ __launch_bounds__(GB_BLK) void k_sgather(const float* __restrict__ feat,
                                                    const ushort_t* __restrict__ featb,
                                                    const float* __restrict__ bias,
                                                    const ushort_t* __restrict__ tblT,
                                                    const vi2* __restrict__ ep,
                                                    float* __restrict__ out) {
    __shared__ vi2 stg[GB_CAP];                          // 12 KB
    __shared__ vi2 srt[GB_CAP];                          // 12 KB
    __shared__ int cnt[BUCK_NODES], cnt2[BUCK_NODES], off[BUCK_NODES];
    __shared__ int ss[GB_BLK];

    const int t = threadIdx.x;
    const int lane = t & 63;
    const int wid = t >> 6;
    const int b = blockIdx.x;
    if (t < BUCK_NODES) { cnt[t] = 0; cnt2[t] = 0; }

    // run descriptors from transposed table rows (contiguous reads)
    const ushort_t* rb  = tblT + (size_t)b * NCHUNK;
    const ushort_t* rb1 = tblT + (size_t)(b + 1) * NCHUNK;
    const int c0 = t, c1 = t + GB_BLK;
    int o00 = 0, o01 = 0, o10 = 0, o11 = 0;
    if (c0 < NCHUNK) { o00 = rb[c0]; o01 = rb1[c0]; }
    if (c1 < NCHUNK) { o10 = rb[c1]; o11 = rb1[c1]; }
    const int len = (o01 - o00) + (o11 - o10);
    ss[t] = len;
    __syncthreads();
    for (int o = 1; o < GB_BLK; o <<= 1) {
        int x = (t >= o) ? ss[t - o] : 0;
        __syncthreads();
        ss[t] += x;
        __syncthreads();
    }
    const int base = ss[t] - len;
    const int nTot = ss[GB_BLK - 1];

    // pass 1: deterministic staging + count
    int g = base;
    for (int e = o00; e < o01; ++e, ++g)
        if (g < GB_CAP) {
            vi2 v = ep[c0 * CHUNK + e];
            stg[g] = v;
            atomicAdd(&cnt[(unsigned)v.x >> 24], 1);
        }
    for (int e = o10; e < o11; ++e, ++g)
        if (g < GB_CAP) {
            vi2 v = ep[c1 * CHUNK + e];
            stg[g] = v;
            atomicAdd(&cnt[(unsigned)v.x >> 24], 1);
        }
    __syncthreads();

    // inclusive scan cnt -> off (64 entries)
    if (t < BUCK_NODES) off[t] = cnt[t];
    __syncthreads();
    for (int d = 1; d < BUCK_NODES; d <<= 1) {
        int x = 0;
        if (t < BUCK_NODES && t >= d) x = off[t - d];
        __syncthreads();
        if (t < BUCK_NODES) off[t] += x;
        __syncthreads();
    }

    // pass 2: scatter into node-sorted list
    const int nStg = nTot < GB_CAP ? nTot : GB_CAP;
    for (int i = t; i < nStg; i += GB_BLK) {
        vi2 v = stg[i];
        int r = (unsigned)v.x >> 24;
        int pos = off[r] - cnt[r] + atomicAdd(&cnt2[r], 1);
        srt[pos] = v;
    }
    __syncthreads();

    // phase 5: per-node register accumulation
    const int col = lane & 31;
    const int half = lane >> 5;
    const vf2 b2 = ((const vf2*)bias)[col];
    for (int rr = 0; rr < 16; ++rr) {
        const int r = wid * 16 + rr;
        const int cc = cnt[r];
        const int s0 = off[r] - cc;
        float a0 = 0.f, a1 = 0.f;
        for (int i = 0; i < cc; i += 8) {
#pragma unroll
            for (int k = 0; k < 4; ++k) {
                const int ei = i + 2 * k + half;
                vi2 e = (ei < cc) ? srt[s0 + ei] : (vi2){0, 0};
                const float w = __int_as_float(e.y);
                const int sidx = e.x & 0xFFFFFF;
                if (BF16) {
                    unsigned d = *((const unsigned*)(featb + (size_t)sidx * D_FEAT) + col);
                    a0 = fmaf(w, __uint_as_float(d << 16), a0);
                    a1 = fmaf(w, __uint_as_float(d & 0xFFFF0000u), a1);
                } else {
                    vf2 fv = *((const vf2*)(feat + (size_t)sidx * D_FEAT) + col);
                    a0 = fmaf(w, fv.x, a0);
                    a1 = fmaf(w, fv.y, a1);
                }
            }
        }
        a0 += __shfl_xor(a0, 32);
        a1 += __shfl_xor(a1, 32);
        const int node = b * BUCK_NODES + r;
        if (half == 0 && node < N_NODES) {
            vf2 o = {a0 + b2.x, a1 + b2.y};
            __builtin_nontemporal_store(o, (vf2*)(out + (size_t)node * D_FEAT) + col);
        }
    }
    __syncthreads();

    // tail (nTot > GB_CAP; ~never at 16 sigma): after the epilogue barrier.
    if (nTot > GB_CAP) {
        int g2 = base;
        for (int e = o00; e < o01; ++e, ++g2)
            if (g2 >= GB_CAP) {
                vi2 v = ep[c0 * CHUNK + e];
                int node = b * BUCK_NODES + (int)((unsigned)v.x >> 24);
                float w = __int_as_float(v.y);
                int sidx = v.x & 0xFFFFFF;
                for (int d2 = 0; d2 < D_FEAT; ++d2)
                    atomicAdd(&out[(size_t)node * D_FEAT + d2], w * feat[(size_t)sidx * D_FEAT + d2]);
            }
        for (int e = o10; e < o11; ++e, ++g2)
            if (g2 >= GB_CAP) {
                vi2 v = ep[c1 * CHUNK + e];
                int node = b * BUCK_NODES + (int)((unsigned)v.x >> 24);
                float w = __int_as_float(v.y);
                int sidx = v.x & 0xFFFFFF;
                for (int d2 = 0; d2 < D_FEAT; ++d2)
                    atomicAdd(&out[(size_t)node * D_FEAT + d2], w * feat[(size_t)sidx * D_FEAT + d2]);
            }
    }
}

// ---------------- fallback (ws too small): direct atomic path ---------------
__global__ void init_out_kernel(const float* __restrict__ bias,
                                float* __restrict__ out) {
    int i = blockIdx.x * blockDim.x + threadIdx.x;
    if (i < N_NODES * D_FEAT) out[i] = bias[i & (D_FEAT - 1)];
}

__global__ void edge_scatter_kernel(const float* __restrict__ feat,
                                    const float* __restrict__ weight,
                                    const int* __restrict__ src,
                                    const int* __restrict__ dst,
                                    float* __restrict__ out) {
    int e = blockIdx.x * 4 + (threadIdx.x >> 6);
    int lane = threadIdx.x & 63;
    if (e < N_EDGES) {
        atomicAdd(&out[dst[e] * D_FEAT + lane], weight[e] * feat[src[e] * D_FEAT + lane]);
    }
}

extern "C" void kernel_launch(void* const* d_in, const int* in_sizes, int n_in,
                              void* d_out, int out_size, void* d_ws, size_t ws_size,
                              hipStream_t stream) {
    const float* feat   = (const float*)d_in[0];
    const float* weight = (const float*)d_in[1];
    const float* bias   = (const float*)d_in[2];
    const int*   src    = (const int*)d_in[3];
    const int*   dst    = (const int*)d_in[4];
    float* out = (float*)d_out;

    if (ws_size < WS_MED) {
        int total = N_NODES * D_FEAT;
        init_out_kernel<<<(total + 255) / 256, 256, 0, stream>>>(bias, out);
        edge_scatter_kernel<<<(N_EDGES + 3) / 4, 256, 0, stream>>>(feat, weight, src, dst, out);
        return;
    }

    char* ws = (char*)d_ws;
    ushort_t* tbl   = (ushort_t*)(ws + OFF_TBL);
    ushort_t* tblT  = (ushort_t*)(ws + OFF_TBLT);
    vi2*      ep    = (vi2*)(ws + OFF_EP);
    ushort_t* featb = (ushort_t*)(ws + OFF_FEATB);
    const bool use_bf16 = (ws_size >= WS_FULL);

    if (use_bf16) {
        k_bin<1><<<NCHUNK + PREP_BLOCKS, BIN_BLK, 0, stream>>>(src, dst, weight, feat, featb, tbl, ep);
        k_ttrans<<<TT_CT * TT_BT, 256, 0, stream>>>(tbl, tblT);
        k_sgather<1><<<NBUCK, GB_BLK, 0, stream>>>(feat, featb, bias, tblT, ep, out);
    } else {
        k_bin<0><<<NCHUNK, BIN_BLK, 0, stream>>>(src, dst, weight, feat, featb, tbl, ep);
        k_ttrans<<<TT_CT * TT_BT, 256, 0, stream>>>(tbl, tblT);
        k_sgather<0><<<NBUCK, GB_BLK, 0, stream>>>(feat, featb, bias, tblT, ep, out);
    }
}

// Round 13
// 100.076 us; speedup vs baseline: 1.0308x; 1.0308x over previous
//
#include <hip/hip_runtime.h>

#define N_NODES 100000
#define N_EDGES 1600000
#define D_FEAT  64
#define NFEAT_ELEM (N_NODES * D_FEAT)                    // 6,400,000

#define BUCK_SHIFT 6
#define BUCK_NODES 64
#define NBUCK ((N_NODES + BUCK_NODES - 1) / BUCK_NODES)  // 1563
#define NB1 (NBUCK + 1)

#define CHUNK   4096
#define NCHUNK  ((N_EDGES + CHUNK - 1) / CHUNK)          // 391
#define BIN_BLK 256
#define BIN_EPT (CHUNK / BIN_BLK)                        // 16
#define SCAN_PER ((NBUCK + BIN_BLK - 1) / BIN_BLK)       // 7
#define PREP_BLOCKS 128

// gather: 2 adjacent buckets (128 nodes) per 512-thread block
#define GB_BLK   512
#define GB_NODES 128
#define NGRP ((NBUCK + 1) / 2)                           // 782
#define GB_CAP   2816                                    // mean 2048, +17 sigma

// transpose tiling
#define TT_CT ((NCHUNK + 63) / 64)                       // 7
#define TT_BT ((NB1 + 63) / 64)                          // 25

typedef float          vf4 __attribute__((ext_vector_type(4)));
typedef float          vf2 __attribute__((ext_vector_type(2)));
typedef int            vi2 __attribute__((ext_vector_type(2)));
typedef unsigned short vu4 __attribute__((ext_vector_type(4)));
typedef unsigned short ushort_t;

// ---------------------------------------------------------------------------
// Workspace: tbl (chunk-major run offsets) | tblT (bucket-major transpose) |
//            ep (chunk-major sorted payload) | featb (bf16 feat).
// ---------------------------------------------------------------------------
#define TBL_BYTES  (NCHUNK * NB1 * 2)
#define OFF_TBL    0
#define OFF_TBLT   (((OFF_TBL + TBL_BYTES) + 255) & ~255)
#define OFF_EP     (((OFF_TBLT + NB1 * NCHUNK * 2) + 255) & ~255)
#define OFF_FEATB  (OFF_EP + N_EDGES * 8)
#define WS_MED     (size_t)OFF_FEATB
#define WS_FULL    (size_t)(OFF_FEATB + (size_t)NFEAT_ELEM * 2)

// Chunk-major binning + fused bf16 prep (role-split grid).
template <int BF16>
__global__ __launch_bounds__(BIN_BLK) void k_bin(const int* __restrict__ src,
                                                 const int* __restrict__ dst,
                                                 const float* __restrict__ weight,
                                                 const float* __restrict__ feat,
                                                 ushort_t* __restrict__ featb,
                                                 ushort_t* __restrict__ tbl,
                                                 vi2* __restrict__ ep) {
    if (blockIdx.x >= NCHUNK) {                          // prep role
        if (!BF16) return;
        const int stride = PREP_BLOCKS * BIN_BLK;
        for (int i = (blockIdx.x - NCHUNK) * BIN_BLK + threadIdx.x;
             i < NFEAT_ELEM / 4; i += stride) {
            vf4 x = ((const vf4*)feat)[i];
            vu4 r;
#pragma unroll
            for (int k = 0; k < 4; ++k) {
                unsigned bb = __float_as_uint(x[k]);
                r[k] = (ushort_t)((bb + 0x7fffu + ((bb >> 16) & 1u)) >> 16);
            }
            __builtin_nontemporal_store(r, (vu4*)featb + i);
        }
        return;
    }

    __shared__ vi2 schunk[CHUNK];                        // 32 KB
    __shared__ int lcnt[NBUCK];                          // 6.25 KB
    __shared__ int ss[BIN_BLK];
    const int t = threadIdx.x;
    const int c = blockIdx.x;
    const int e0 = c * CHUNK;
    const int chunkN = (N_EDGES - e0 < CHUNK) ? (N_EDGES - e0) : CHUNK;

    for (int i = t; i < NBUCK; i += BIN_BLK) lcnt[i] = 0;
    __syncthreads();

    int bk[BIN_EPT], rk[BIN_EPT], xk[BIN_EPT], wk[BIN_EPT];
#pragma unroll
    for (int k = 0; k < BIN_EPT; ++k) {
        const int e = e0 + t + k * BIN_BLK;              // coalesced
        bk[k] = -1;
        if (e < N_EDGES) {
            int v = __builtin_nontemporal_load(dst + e);
            int s = __builtin_nontemporal_load(src + e);
            wk[k] = __builtin_nontemporal_load((const int*)weight + e);
            bk[k] = v >> BUCK_SHIFT;
            xk[k] = ((v & (BUCK_NODES - 1)) << 24) | s;  // src < 2^17
            rk[k] = atomicAdd(&lcnt[bk[k]], 1);
        }
    }
    __syncthreads();

    // blocked exclusive scan of lcnt (1563) -> in-place starts + table row
    int v7[SCAN_PER];
    const int lo = t * SCAN_PER;
    int s = 0;
#pragma unroll
    for (int k = 0; k < SCAN_PER; ++k) {
        const int i = lo + k;
        v7[k] = (i < NBUCK) ? lcnt[i] : 0;
        s += v7[k];
    }
    ss[t] = s;
    __syncthreads();
    for (int off = 1; off < BIN_BLK; off <<= 1) {
        int x = (t >= off) ? ss[t - off] : 0;
        __syncthreads();
        ss[t] += x;
        __syncthreads();
    }
    int run = ss[t] - s;
    ushort_t* row = tbl + (size_t)c * NB1;
#pragma unroll
    for (int k = 0; k < SCAN_PER; ++k) {
        const int i = lo + k;
        if (i < NBUCK) {
            row[i] = (ushort_t)run;
            lcnt[i] = run;
            run += v7[k];
        }
    }
    if (t == BIN_BLK - 1) row[NBUCK] = (ushort_t)chunkN;
    __syncthreads();

#pragma unroll
    for (int k = 0; k < BIN_EPT; ++k)
        if (bk[k] >= 0) schunk[lcnt[bk[k]] + rk[k]] = (vi2){xk[k], wk[k]};
    __syncthreads();

    for (int i = t; i < chunkN; i += BIN_BLK)            // contiguous stream
        __builtin_nontemporal_store(schunk[i], ep + e0 + i);
}

// 64x64 LDS-tiled transpose: tbl[c][b] -> tblT[b][c].
__global__ __launch_bounds__(256) void k_ttrans(const ushort_t* __restrict__ tbl,
                                                ushort_t* __restrict__ tblT) {
    __shared__ ushort_t tile[64][65];
    const int t = threadIdx.x;
    const int c0 = (blockIdx.x % TT_CT) * 64;
    const int b0 = (blockIdx.x / TT_CT) * 64;
    for (int idx = t; idx < 4096; idx += 256) {
        int cl = idx >> 6, bl = idx & 63;
        int c = c0 + cl, bb = b0 + bl;
        tile[bl][cl] = (c < NCHUNK && bb < NB1) ? tbl[(size_t)c * NB1 + bb] : (ushort_t)0;
    }
    __syncthreads();
    for (int idx = t; idx < 4096; idx += 256) {
        int bl = idx >> 6, cl = idx & 63;
        int c = c0 + cl, bb = b0 + bl;
        if (c < NCHUNK && bb < NB1) tblT[(size_t)bb * NCHUNK + c] = tile[bl][cl];
    }
}

// One 512-thread block per 2-bucket group (128 nodes). The group's edges are
// CONTIGUOUS [tblT[b0][c], tblT[b0+2][c]) within each chunk (buckets adjacent
// in chunk-sorted order) -> fewer partial-line reads; the middle offset
// distinguishes the two buckets. Stage+count -> scan -> sort -> per-node
// register accumulation (half-wave pair trick). 8 waves, ~48.5 KB LDS ->
// 3 blocks/CU = 24 waves/CU.
template <int BF16>
__global__ __launch_bounds__(GB_BLK) void k_sgather(const float* __restrict__ feat,
                                                    const ushort_t* __restrict__ featb,
                                                    const float* __restrict__ bias,
                                                    const ushort_t* __restrict__ tblT,
                                                    const vi2* __restrict__ ep,
                                                    float* __restrict__ out) {
    __shared__ vi2 stg[GB_CAP];                          // 22 KB
    __shared__ vi2 srt[GB_CAP];                          // 22 KB
    __shared__ int cnt[GB_NODES], cnt2[GB_NODES], off[GB_NODES];
    __shared__ int ss[GB_BLK];

    const int t = threadIdx.x;
    const int lane = t & 63;
    const int wid = t >> 6;                              // 0..7
    const int grp = blockIdx.x;
    const int b0 = grp * 2;
    const int bhi = (b0 + 2 <= NBUCK) ? b0 + 2 : NBUCK;
    if (t < GB_NODES) { cnt[t] = 0; cnt2[t] = 0; }

    // contiguous group run in chunk t: [o0, o2), bucket split at o1
    int o0 = 0, o1 = 0, o2 = 0;
    if (t < NCHUNK) {
        o0 = tblT[(size_t)b0 * NCHUNK + t];
        o1 = tblT[(size_t)(b0 + 1) * NCHUNK + t];
        o2 = tblT[(size_t)bhi * NCHUNK + t];
    }
    const int len = o2 - o0;
    ss[t] = len;
    __syncthreads();
    for (int o = 1; o < GB_BLK; o <<= 1) {
        int x = (t >= o) ? ss[t - o] : 0;
        __syncthreads();
        ss[t] += x;
        __syncthreads();
    }
    const int base = ss[t] - len;
    const int nTot = ss[GB_BLK - 1];

    // pass 1: staging (contiguous span read) + count; rewrite node as 7-bit
    int g = base;
    for (int e = o0; e < o2; ++e, ++g)
        if (g < GB_CAP) {
            vi2 v = ep[(size_t)t * CHUNK + e];
            int r = ((e >= o1) ? 64 : 0) + (int)((unsigned)v.x >> 24);
            v.x = (v.x & 0xFFFFFF) | (r << 24);
            stg[g] = v;
            atomicAdd(&cnt[r], 1);
        }
    __syncthreads();

    // inclusive scan cnt -> off (128 entries)
    if (t < GB_NODES) off[t] = cnt[t];
    __syncthreads();
    for (int d = 1; d < GB_NODES; d <<= 1) {
        int x = 0;
        if (t < GB_NODES && t >= d) x = off[t - d];
        __syncthreads();
        if (t < GB_NODES) off[t] += x;
        __syncthreads();
    }

    // pass 2: scatter into node-sorted list
    const int nStg = nTot < GB_CAP ? nTot : GB_CAP;
    for (int i = t; i < nStg; i += GB_BLK) {
        vi2 v = stg[i];
        int r = (unsigned)v.x >> 24;
        int pos = off[r] - cnt[r] + atomicAdd(&cnt2[r], 1);
        srt[pos] = v;
    }
    __syncthreads();

    // phase 5: per-node register accumulation; wave wid owns 16 nodes
    const int col = lane & 31;
    const int half = lane >> 5;
    const vf2 b2 = ((const vf2*)bias)[col];
    for (int rr = 0; rr < 16; ++rr) {
        const int r = wid * 16 + rr;
        const int cc = cnt[r];
        const int s0 = off[r] - cc;
        float a0 = 0.f, a1 = 0.f;
        for (int i = 0; i < cc; i += 8) {
#pragma unroll
            for (int k = 0; k < 4; ++k) {
                const int ei = i + 2 * k + half;
                vi2 e = (ei < cc) ? srt[s0 + ei] : (vi2){0, 0};
                const float w = __int_as_float(e.y);
                const int sidx = e.x & 0xFFFFFF;
                if (BF16) {
                    unsigned d = *((const unsigned*)(featb + (size_t)sidx * D_FEAT) + col);
                    a0 = fmaf(w, __uint_as_float(d << 16), a0);
                    a1 = fmaf(w, __uint_as_float(d & 0xFFFF0000u), a1);
                } else {
                    vf2 fv = *((const vf2*)(feat + (size_t)sidx * D_FEAT) + col);
                    a0 = fmaf(w, fv.x, a0);
                    a1 = fmaf(w, fv.y, a1);
                }
            }
        }
        a0 += __shfl_xor(a0, 32);
        a1 += __shfl_xor(a1, 32);
        const int node = grp * GB_NODES + r;
        if (half == 0 && node < N_NODES) {
            vf2 o = {a0 + b2.x, a1 + b2.y};
            __builtin_nontemporal_store(o, (vf2*)(out + (size_t)node * D_FEAT) + col);
        }
    }
    __syncthreads();

    // tail (nTot > GB_CAP; +17 sigma, ~never): after the epilogue barrier.
    if (nTot > GB_CAP) {
        int g2 = base;
        for (int e = o0; e < o2; ++e, ++g2)
            if (g2 >= GB_CAP) {
                vi2 v = ep[(size_t)t * CHUNK + e];
                int r = ((e >= o1) ? 64 : 0) + (int)((unsigned)v.x >> 24);
                int node = grp * GB_NODES + r;
                float w = __int_as_float(v.y);
                int sidx = v.x & 0xFFFFFF;
                if (node < N_NODES)
                    for (int d2 = 0; d2 < D_FEAT; ++d2)
                        atomicAdd(&out[(size_t)node * D_FEAT + d2], w * feat[(size_t)sidx * D_FEAT + d2]);
            }
    }
}

// ---------------- fallback (ws too small): direct atomic path ---------------
__global__ void init_out_kernel(const float* __restrict__ bias,
                                float* __restrict__ out) {
    int i = blockIdx.x * blockDim.x + threadIdx.x;
    if (i < N_NODES * D_FEAT) out[i] = bias[i & (D_FEAT - 1)];
}

__global__ void edge_scatter_kernel(const float* __restrict__ feat,
                                    const float* __restrict__ weight,
                                    const int* __restrict__ src,
                                    const int* __restrict__ dst,
                                    float* __restrict__ out) {
    int e = blockIdx.x * 4 + (threadIdx.x >> 6);
    int lane = threadIdx.x & 63;
    if (e < N_EDGES) {
        atomicAdd(&out[dst[e] * D_FEAT + lane], weight[e] * feat[src[e] * D_FEAT + lane]);
    }
}

extern "C" void kernel_launch(void* const* d_in, const int* in_sizes, int n_in,
                              void* d_out, int out_size, void* d_ws, size_t ws_size,
                              hipStream_t stream) {
    const float* feat   = (const float*)d_in[0];
    const float* weight = (const float*)d_in[1];
    const float* bias   = (const float*)d_in[2];
    const int*   src    = (const int*)d_in[3];
    const int*   dst    = (const int*)d_in[4];
    float* out = (float*)d_out;

    if (ws_size < WS_MED) {
        int total = N_NODES * D_FEAT;
        init_out_kernel<<<(total + 255) / 256, 256, 0, stream>>>(bias, out);
        edge_scatter_kernel<<<(N_EDGES + 3) / 4, 256, 0, stream>>>(feat, weight, src, dst, out);
        return;
    }

    char* ws = (char*)d_ws;
    ushort_t* tbl   = (ushort_t*)(ws + OFF_TBL);
    ushort_t* tblT  = (ushort_t*)(ws + OFF_TBLT);
    vi2*      ep    = (vi2*)(ws + OFF_EP);
    ushort_t* featb = (ushort_t*)(ws + OFF_FEATB);
    const bool use_bf16 = (ws_size >= WS_FULL);

    if (use_bf16) {
        k_bin<1><<<NCHUNK + PREP_BLOCKS, BIN_BLK, 0, stream>>>(src, dst, weight, feat, featb, tbl, ep);
        k_ttrans<<<TT_CT * TT_BT, 256, 0, stream>>>(tbl, tblT);
        k_sgather<1><<<NGRP, GB_BLK, 0, stream>>>(feat, featb, bias, tblT, ep, out);
    } else {
        k_bin<0><<<NCHUNK, BIN_BLK, 0, stream>>>(src, dst, weight, feat, featb, tbl, ep);
        k_ttrans<<<TT_CT * TT_BT, 256, 0, stream>>>(tbl, tblT);
        k_sgather<0><<<NGRP, GB_BLK, 0, stream>>>(feat, featb, bias, tblT, ep, out);
    }
}